// Round 1
// baseline (1940.912 us; speedup 1.0000x reference)
//
#include <hip/hip_runtime.h>

// ---------------------------------------------------------------------------
// CasualGraph: 3 layers of  source = T^T (T x);  x = LN(source + x0)
// then per-hyperedge masked mean of final (pre-norm) source, global max over
// edges. All heavy matmuls in bf16 MFMA (16x16x32), fp32 accumulate.
//
// Layouts (d-major activations so every GEMM is A[M,K] x B[N,K], K-contig):
//   Tb  [8192][8192] bf16   = T
//   Tt  [8192][8192] bf16   = T^T
//   Htb [4096][8192] bf16   = H^T
//   x0t [256][8192]  f32    = x0^T (residual, kept fp32)
//   Xt  [256][8192]  bf16   = current layer input, d-major
//   tt  [256][8192]  bf16   = (T x)^T
//   st  [256][8192]  f32    = source^T (layers 0,1 for LN)
//   stb [256][8192]  bf16   = source^T bf16 (layer 2, feeds edge GEMM)
//   sumsT [256][4096] f32   = (H^T source)^T
// ---------------------------------------------------------------------------

typedef __bf16 bf16;
typedef __bf16 bf16x8 __attribute__((ext_vector_type(8)));
typedef float f32x4 __attribute__((ext_vector_type(4)));

// ---------------------------------------------------------------------------
// GEMM: C[m][n] = sum_k A[m][k] * B[n][k]; A,B bf16 (K-contiguous rows).
// BK=32, 256 threads = 4 waves in 2x2, wave tile (BM/2)x(BN/2) of 16x16 MFMAs.
// Double-buffered LDS + register prefetch: 1 barrier per K-iter.
// MODE: 1 = write fp32 Cf, 2 = write bf16 Cb, 3 = both.
// ---------------------------------------------------------------------------
template <int BM, int BN, int MODE>
__global__ __launch_bounds__(256) void gemm_bt(const bf16* __restrict__ A,
                                               const bf16* __restrict__ B,
                                               float* __restrict__ Cf,
                                               bf16* __restrict__ Cb,
                                               int M, int N, int K) {
  constexpr int BK = 32;
  constexpr int WM = BM / 2, WN = BN / 2;
  constexpr int TM = WM / 16, TN = WN / 16;
  constexpr int LA = (BM * BK) / (256 * 8);  // 16B loads/thread for A tile
  constexpr int LB = (BN * BK) / (256 * 8);  // 16B loads/thread for B tile

  __shared__ __align__(16) bf16 As[2][BM * BK];
  __shared__ __align__(16) bf16 Bs[2][BN * BK];

  const int t = threadIdx.x;
  const int w = t >> 6, l = t & 63;
  const int lm = l & 15;        // fragment row (A.m / B.n)
  const int kq = l >> 4;        // k-quad: k = kq*8 .. kq*8+7
  const int wm = (w >> 1) * WM;
  const int wn = (w & 1) * WN;
  const int m0 = blockIdx.y * BM;
  const int n0 = blockIdx.x * BN;

  // staging: thread t covers row (t>>2) [+64 per extra load], k-col (t&3)*8
  const int arow = t >> 2, acol = (t & 3) * 8;
  const bf16* gA = A + (size_t)(m0 + arow) * K + acol;
  const bf16* gB = B + (size_t)(n0 + arow) * K + acol;

  int4 ra[LA], rb[LB];
  auto loadAB = [&](int k0) {
#pragma unroll
    for (int q = 0; q < LA; ++q)
      ra[q] = *(const int4*)(gA + (size_t)(q * 64) * K + k0);
#pragma unroll
    for (int q = 0; q < LB; ++q)
      rb[q] = *(const int4*)(gB + (size_t)(q * 64) * K + k0);
  };
  auto writeLDS = [&](int buf) {
    // LDS offset (q*64 + t>>2)*BK + (t&3)*8 == q*2048 + t*8  (BK==32)
#pragma unroll
    for (int q = 0; q < LA; ++q) *(int4*)(&As[buf][q * 2048 + t * 8]) = ra[q];
#pragma unroll
    for (int q = 0; q < LB; ++q) *(int4*)(&Bs[buf][q * 2048 + t * 8]) = rb[q];
  };

  f32x4 acc[TM][TN];
#pragma unroll
  for (int i = 0; i < TM; ++i)
#pragma unroll
    for (int j = 0; j < TN; ++j) acc[i][j] = (f32x4)(0.0f);

  const int nk = K / BK;
  loadAB(0);
  writeLDS(0);
  if (nk > 1) loadAB(BK);
  __syncthreads();

  for (int kk = 0; kk < nk; ++kk) {
    const int cur = kk & 1;
    if (kk + 1 < nk) writeLDS(cur ^ 1);      // regs hold tile kk+1
    if (kk + 2 < nk) loadAB((kk + 2) * BK);  // prefetch tile kk+2

    bf16x8 af[TM], bfr[TN];
#pragma unroll
    for (int i = 0; i < TM; ++i)
      af[i] = *(const bf16x8*)(&As[cur][(wm + i * 16 + lm) * BK + kq * 8]);
#pragma unroll
    for (int j = 0; j < TN; ++j)
      bfr[j] = *(const bf16x8*)(&Bs[cur][(wn + j * 16 + lm) * BK + kq * 8]);
#pragma unroll
    for (int i = 0; i < TM; ++i)
#pragma unroll
      for (int j = 0; j < TN; ++j)
        acc[i][j] = __builtin_amdgcn_mfma_f32_16x16x32_bf16(af[i], bfr[j],
                                                            acc[i][j], 0, 0, 0);
    __syncthreads();
  }

  // epilogue: C/D layout col = lane&15, row = kq*4 + r
#pragma unroll
  for (int i = 0; i < TM; ++i) {
    const int mrow = m0 + wm + i * 16 + kq * 4;
#pragma unroll
    for (int j = 0; j < TN; ++j) {
      const int col = n0 + wn + j * 16 + lm;
#pragma unroll
      for (int r = 0; r < 4; ++r) {
        const size_t idx = (size_t)(mrow + r) * N + col;
        const float v = acc[i][j][r];
        if (MODE & 1) Cf[idx] = v;
        if (MODE & 2) Cb[idx] = (bf16)v;
      }
    }
  }
}

// ---------------------------------------------------------------------------
// 64x64 LDS tile transpose/convert: src [R][C] f32 ->
//   cpy [R][C] bf16 (optional), trb [C][R] bf16 (optional), trf [C][R] f32.
// ---------------------------------------------------------------------------
__global__ __launch_bounds__(256) void transpose_conv(
    const float* __restrict__ src, int R, int C, bf16* __restrict__ cpy,
    bf16* __restrict__ trb, float* __restrict__ trf) {
  __shared__ float tile[64][65];
  const int t = threadIdx.x;
  const int col = t & 63, rb4 = t >> 6;
  const int r0 = blockIdx.y * 64, c0 = blockIdx.x * 64;
#pragma unroll
  for (int rr = 0; rr < 64; rr += 4) {
    const int row = rr + rb4;
    const float v = src[(size_t)(r0 + row) * C + c0 + col];
    tile[row][col] = v;
    if (cpy) cpy[(size_t)(r0 + row) * C + c0 + col] = (bf16)v;
  }
  __syncthreads();
#pragma unroll
  for (int rr = 0; rr < 64; rr += 4) {
    const int row = rr + rb4;
    const float v = tile[col][row];  // stride-65 read: conflict-free
    const size_t di = (size_t)(c0 + row) * R + r0 + col;
    if (trb) trb[di] = (bf16)v;
    if (trf) trf[di] = v;
  }
}

// ---------------------------------------------------------------------------
// LayerNorm over d for each node i (d-major buffers). block (32 nodes, 8 d-grp)
// ---------------------------------------------------------------------------
__global__ __launch_bounds__(256) void ln_kernel(const float* __restrict__ st,
                                                 const float* __restrict__ x0t,
                                                 const float* __restrict__ gamma,
                                                 const float* __restrict__ beta,
                                                 bf16* __restrict__ Xt) {
  const int tx = threadIdx.x;  // node lane 0..31
  const int ty = threadIdx.y;  // d-group 0..7
  const int i = blockIdx.x * 32 + tx;
  float vbuf[32];
  float s = 0.f, s2 = 0.f;
#pragma unroll
  for (int dd = 0; dd < 32; ++dd) {
    const int d = ty * 32 + dd;
    const float v = st[(size_t)d * 8192 + i] + x0t[(size_t)d * 8192 + i];
    vbuf[dd] = v;
    s += v;
    s2 += v * v;
  }
  __shared__ float S[8][32], Q[8][32];
  S[ty][tx] = s;
  Q[ty][tx] = s2;
  __syncthreads();
  __shared__ float MU[32], RS[32];
  if (ty == 0) {
    float a = 0.f, b = 0.f;
#pragma unroll
    for (int r = 0; r < 8; ++r) {
      a += S[r][tx];
      b += Q[r][tx];
    }
    const float mu = a * (1.0f / 256.0f);
    const float var = b * (1.0f / 256.0f) - mu * mu;
    MU[tx] = mu;
    RS[tx] = rsqrtf(var + 1e-5f);
  }
  __syncthreads();
  const float mu = MU[tx], rs = RS[tx];
#pragma unroll
  for (int dd = 0; dd < 32; ++dd) {
    const int d = ty * 32 + dd;
    const float y = (vbuf[dd] - mu) * rs * gamma[d] + beta[d];
    Xt[(size_t)d * 8192 + i] = (bf16)y;
  }
}

// ---------------------------------------------------------------------------
// inv_counts[e] = 1 / sum_i H[i][e]   (from Htb rows, coalesced)
// ---------------------------------------------------------------------------
__global__ __launch_bounds__(256) void counts_kernel(const bf16* __restrict__ Htb,
                                                     float* __restrict__ invc) {
  const int e = blockIdx.x;
  const bf16* row = Htb + (size_t)e * 8192;
  float s = 0.f;
  for (int i = threadIdx.x; i < 8192; i += 256) s += (float)row[i];
  __shared__ float red[256];
  red[threadIdx.x] = s;
  __syncthreads();
  for (int k = 128; k > 0; k >>= 1) {
    if (threadIdx.x < k) red[threadIdx.x] += red[threadIdx.x + k];
    __syncthreads();
  }
  if (threadIdx.x == 0) invc[e] = 1.0f / red[0];
}

// ---------------------------------------------------------------------------
// out[d] = max_e sumsT[d][e] * invc[e]
// ---------------------------------------------------------------------------
__global__ __launch_bounds__(256) void final_max(const float* __restrict__ sumsT,
                                                 const float* __restrict__ invc,
                                                 float* __restrict__ out) {
  const int d = blockIdx.x;
  float m = -3.4e38f;
  for (int e = threadIdx.x; e < 4096; e += 256)
    m = fmaxf(m, sumsT[(size_t)d * 4096 + e] * invc[e]);
  __shared__ float red[256];
  red[threadIdx.x] = m;
  __syncthreads();
  for (int k = 128; k > 0; k >>= 1) {
    if (threadIdx.x < k)
      red[threadIdx.x] = fmaxf(red[threadIdx.x], red[threadIdx.x + k]);
    __syncthreads();
  }
  if (threadIdx.x == 0) out[d] = red[0];
}

// ---------------------------------------------------------------------------
extern "C" void kernel_launch(void* const* d_in, const int* in_sizes, int n_in,
                              void* d_out, int out_size, void* d_ws,
                              size_t ws_size, hipStream_t stream) {
  const float* x0 = (const float*)d_in[0];    // [8192][256]
  const float* T = (const float*)d_in[1];     // [8192][8192]
  const float* H = (const float*)d_in[2];     // [8192][4096]
  const float* gamma = (const float*)d_in[3]; // [256]
  const float* beta = (const float*)d_in[4];  // [256]
  // num_layers (d_in[5]) is fixed at 3 by the reference setup.

  constexpr int Nn = 8192, E = 4096, D = 256, K = 8192;

  char* w = (char*)d_ws;
  size_t off = 0;
  auto carve = [&](size_t bytes) {
    char* p = w + off;
    off += (bytes + 255) & ~(size_t)255;
    return p;
  };
  bf16* Tb = (bf16*)carve((size_t)Nn * Nn * 2);
  bf16* Tt = (bf16*)carve((size_t)Nn * Nn * 2);
  bf16* Htb = (bf16*)carve((size_t)E * Nn * 2);
  float* x0t = (float*)carve((size_t)D * Nn * 4);
  bf16* Xt = (bf16*)carve((size_t)D * Nn * 2);
  bf16* tt = (bf16*)carve((size_t)D * Nn * 2);
  float* st = (float*)carve((size_t)D * Nn * 4);
  bf16* stb = (bf16*)carve((size_t)D * Nn * 2);
  float* sumsT = (float*)carve((size_t)D * E * 4);
  float* invc = (float*)carve((size_t)E * 4);

  if (off > ws_size) {  // workspace too small: fail gracefully (out = 0)
    hipMemsetAsync(d_out, 0, (size_t)out_size * 4, stream);
    return;
  }

  // one-time layout prep
  transpose_conv<<<dim3(128, 128), 256, 0, stream>>>(T, Nn, Nn, Tb, Tt, nullptr);
  transpose_conv<<<dim3(64, 128), 256, 0, stream>>>(H, Nn, E, nullptr, Htb, nullptr);
  transpose_conv<<<dim3(4, 128), 256, 0, stream>>>(x0, Nn, D, nullptr, Xt, x0t);
  counts_kernel<<<E, 256, 0, stream>>>(Htb, invc);

  for (int layer = 0; layer < 3; ++layer) {
    // tt[d][j] = sum_k Xt[d][k] * Tb[j][k]        (t = T @ x)
    gemm_bt<64, 128, 2><<<dim3(64, 4), 256, 0, stream>>>(Xt, Tb, nullptr, tt,
                                                         D, Nn, K);
    if (layer < 2) {
      // st[d][i] = sum_j tt[d][j] * Tt[i][j]      (source = T^T @ t), fp32
      gemm_bt<64, 128, 1><<<dim3(64, 4), 256, 0, stream>>>(tt, Tt, st, nullptr,
                                                           D, Nn, K);
      ln_kernel<<<dim3(256), dim3(32, 8), 0, stream>>>(st, x0t, gamma, beta, Xt);
    } else {
      // last layer: only bf16 source needed (feeds edge GEMM; no LN use)
      gemm_bt<64, 128, 2><<<dim3(64, 4), 256, 0, stream>>>(tt, Tt, nullptr, stb,
                                                           D, Nn, K);
    }
  }

  // sumsT[d][e] = sum_i stb[d][i] * Htb[e][i]
  gemm_bt<64, 64, 1><<<dim3(64, 4), 256, 0, stream>>>(stb, Htb, sumsT, nullptr,
                                                      D, E, K);
  final_max<<<D, 256, 0, stream>>>(sumsT, invc, (float*)d_out);
}

// Round 2
// 1824.923 us; speedup vs baseline: 1.0636x; 1.0636x over previous
//
#include <hip/hip_runtime.h>

// ---------------------------------------------------------------------------
// CasualGraph: 3 layers of  source = T^T (T x);  x = LN(source + x0)
// then per-hyperedge masked mean of final (pre-norm) source, global max.
// bf16 MFMA (16x16x32), fp32 accumulate, split-K=4 for occupancy.
//
// Layouts (d-major activations so every GEMM is A[M,K] x B[N,K], K-contig):
//   Tb  [8192][8192] bf16 = T           Tt [8192][8192] bf16 = T^T
//   Htb [4096][8192] bf16 = H^T         x0t [256][8192] f32 = x0^T
//   Xt  [256][8192]  bf16 = layer in    tt [256][8192] bf16 = (T x)^T
//   stb [256][8192]  bf16 = source^T (layer 2)
//   P   [4][256*8192] f32 = split-K partials (shared by all GEMMs)
// ---------------------------------------------------------------------------

typedef __bf16 bf16;
typedef __bf16 bf16x8 __attribute__((ext_vector_type(8)));
typedef float f32x4 __attribute__((ext_vector_type(4)));

// ---------------------------------------------------------------------------
// GEMM: P[s][m][n] = sum_{k in split s} A[m][k] * B[n][k]; A,B bf16.
// BK=32, 256 threads = 4 waves in 2x2. Double-buffered LDS + reg prefetch.
// LDS layout XOR-swizzled: 16B block column c' = c ^ ((row>>1)&3) so the
// 16-lane b128 fragment reads hit all 8 bank-groups (2-way alias = free).
// ---------------------------------------------------------------------------
template <int BM, int BN>
__global__ __launch_bounds__(256) void gemm_bt(const bf16* __restrict__ A,
                                               const bf16* __restrict__ B,
                                               float* __restrict__ P,
                                               int M, int N, int K, int Ks) {
  constexpr int BK = 32;
  constexpr int WM = BM / 2, WN = BN / 2;
  constexpr int TM = WM / 16, TN = WN / 16;
  constexpr int LA = (BM * BK) / (256 * 8);
  constexpr int LB = (BN * BK) / (256 * 8);

  __shared__ __align__(16) bf16 As[2][BM * BK];
  __shared__ __align__(16) bf16 Bs[2][BN * BK];

  const int t = threadIdx.x;
  const int w = t >> 6, l = t & 63;
  const int lm = l & 15;  // fragment row (A.m / B.n)
  const int kq = l >> 4;  // k-quad
  const int wm = (w >> 1) * WM;
  const int wn = (w & 1) * WN;
  const int m0 = blockIdx.y * BM;
  const int n0 = blockIdx.x * BN;
  const int kbase = blockIdx.z * Ks;

  // staging: thread t covers row (t>>2) [+64 per q], k-col (t&3)*8
  const int arow = t >> 2, acol = (t & 3) * 8;
  const bf16* gA = A + (size_t)(m0 + arow) * K + kbase + acol;
  const bf16* gB = B + (size_t)(n0 + arow) * K + kbase + acol;
  // swizzled write slot (element offset within a 64-row chunk)
  const int wslot = (t >> 2) * 32 + (((t & 3) ^ ((t >> 3) & 3)) * 8);

  int4 ra[LA], rb[LB];
  auto loadAB = [&](int k0) {
#pragma unroll
    for (int q = 0; q < LA; ++q)
      ra[q] = *(const int4*)(gA + (size_t)(q * 64) * K + k0);
#pragma unroll
    for (int q = 0; q < LB; ++q)
      rb[q] = *(const int4*)(gB + (size_t)(q * 64) * K + k0);
  };
  auto writeLDS = [&](int buf) {
#pragma unroll
    for (int q = 0; q < LA; ++q) *(int4*)(&As[buf][q * 2048 + wslot]) = ra[q];
#pragma unroll
    for (int q = 0; q < LB; ++q) *(int4*)(&Bs[buf][q * 2048 + wslot]) = rb[q];
  };

  f32x4 acc[TM][TN];
#pragma unroll
  for (int i = 0; i < TM; ++i)
#pragma unroll
    for (int j = 0; j < TN; ++j) acc[i][j] = (f32x4)(0.0f);

  const int nk = Ks / BK;
  loadAB(0);
  writeLDS(0);
  if (nk > 1) loadAB(BK);
  __syncthreads();

  for (int kk = 0; kk < nk; ++kk) {
    const int cur = kk & 1;
    if (kk + 1 < nk) writeLDS(cur ^ 1);
    if (kk + 2 < nk) loadAB((kk + 2) * BK);

    bf16x8 af[TM], bfr[TN];
#pragma unroll
    for (int i = 0; i < TM; ++i) {
      const int row = wm + i * 16 + lm;
      const int c = (kq ^ ((row >> 1) & 3)) * 8;
      af[i] = *(const bf16x8*)(&As[cur][row * 32 + c]);
    }
#pragma unroll
    for (int j = 0; j < TN; ++j) {
      const int row = wn + j * 16 + lm;
      const int c = (kq ^ ((row >> 1) & 3)) * 8;
      bfr[j] = *(const bf16x8*)(&Bs[cur][row * 32 + c]);
    }
#pragma unroll
    for (int i = 0; i < TM; ++i)
#pragma unroll
      for (int j = 0; j < TN; ++j)
        acc[i][j] = __builtin_amdgcn_mfma_f32_16x16x32_bf16(af[i], bfr[j],
                                                            acc[i][j], 0, 0, 0);
    __syncthreads();
  }

  // epilogue: C/D layout col = lane&15, row = kq*4 + r; write fp32 partial
  float* Pz = P + (size_t)blockIdx.z * M * N;
#pragma unroll
  for (int i = 0; i < TM; ++i) {
    const int mrow = m0 + wm + i * 16 + kq * 4;
#pragma unroll
    for (int j = 0; j < TN; ++j) {
      const int col = n0 + wn + j * 16 + lm;
#pragma unroll
      for (int r = 0; r < 4; ++r)
        Pz[(size_t)(mrow + r) * N + col] = acc[i][j][r];
    }
  }
}

// ---------------------------------------------------------------------------
// out[i] = bf16( sum_s P[s][i] ), float4-vectorized.
// ---------------------------------------------------------------------------
__global__ __launch_bounds__(256) void reduce4_bf16(const float* __restrict__ P,
                                                    bf16* __restrict__ out,
                                                    size_t MN) {
  const size_t i4 = ((size_t)blockIdx.x * 256 + threadIdx.x) * 4;
  if (i4 >= MN) return;
  f32x4 a = *(const f32x4*)(P + i4);
  f32x4 b = *(const f32x4*)(P + MN + i4);
  f32x4 c = *(const f32x4*)(P + 2 * MN + i4);
  f32x4 d = *(const f32x4*)(P + 3 * MN + i4);
  a = a + b + c + d;
  bf16 o[4] = {(bf16)a[0], (bf16)a[1], (bf16)a[2], (bf16)a[3]};
  *(int2*)(out + i4) = *(const int2*)o;
}

// ---------------------------------------------------------------------------
// 64x64 LDS tile transpose/convert: src [R][C] f32 ->
//   cpy [R][C] bf16 (opt), trb [C][R] bf16 (opt), trf [C][R] f32 (opt).
// ---------------------------------------------------------------------------
__global__ __launch_bounds__(256) void transpose_conv(
    const float* __restrict__ src, int R, int C, bf16* __restrict__ cpy,
    bf16* __restrict__ trb, float* __restrict__ trf) {
  __shared__ float tile[64][65];
  const int t = threadIdx.x;
  const int col = t & 63, rb4 = t >> 6;
  const int r0 = blockIdx.y * 64, c0 = blockIdx.x * 64;
#pragma unroll
  for (int rr = 0; rr < 64; rr += 4) {
    const int row = rr + rb4;
    const float v = src[(size_t)(r0 + row) * C + c0 + col];
    tile[row][col] = v;
    if (cpy) cpy[(size_t)(r0 + row) * C + c0 + col] = (bf16)v;
  }
  __syncthreads();
#pragma unroll
  for (int rr = 0; rr < 64; rr += 4) {
    const int row = rr + rb4;
    const float v = tile[col][row];
    const size_t di = (size_t)(c0 + row) * R + r0 + col;
    if (trb) trb[di] = (bf16)v;
    if (trf) trf[di] = v;
  }
}

// ---------------------------------------------------------------------------
// LayerNorm over d, fused 4-way split-K reduce of P. block (32 nodes, 8 dgrp)
// ---------------------------------------------------------------------------
__global__ __launch_bounds__(256) void ln_kernel(const float* __restrict__ P,
                                                 const float* __restrict__ x0t,
                                                 const float* __restrict__ gamma,
                                                 const float* __restrict__ beta,
                                                 bf16* __restrict__ Xt) {
  constexpr size_t MN = (size_t)256 * 8192;
  const int tx = threadIdx.x;
  const int ty = threadIdx.y;
  const int i = blockIdx.x * 32 + tx;
  float vbuf[32];
  float s = 0.f, s2 = 0.f;
#pragma unroll
  for (int dd = 0; dd < 32; ++dd) {
    const int d = ty * 32 + dd;
    const size_t idx = (size_t)d * 8192 + i;
    const float v = P[idx] + P[MN + idx] + P[2 * MN + idx] + P[3 * MN + idx] +
                    x0t[idx];
    vbuf[dd] = v;
    s += v;
    s2 += v * v;
  }
  __shared__ float S[8][32], Q[8][32];
  S[ty][tx] = s;
  Q[ty][tx] = s2;
  __syncthreads();
  __shared__ float MU[32], RS[32];
  if (ty == 0) {
    float a = 0.f, b = 0.f;
#pragma unroll
    for (int r = 0; r < 8; ++r) {
      a += S[r][tx];
      b += Q[r][tx];
    }
    const float mu = a * (1.0f / 256.0f);
    const float var = b * (1.0f / 256.0f) - mu * mu;
    MU[tx] = mu;
    RS[tx] = rsqrtf(var + 1e-5f);
  }
  __syncthreads();
  const float mu = MU[tx], rs = RS[tx];
#pragma unroll
  for (int dd = 0; dd < 32; ++dd) {
    const int d = ty * 32 + dd;
    const float y = (vbuf[dd] - mu) * rs * gamma[d] + beta[d];
    Xt[(size_t)d * 8192 + i] = (bf16)y;
  }
}

// ---------------------------------------------------------------------------
// inv_counts[e] = 1 / sum_i H[i][e]   (from Htb rows, coalesced)
// ---------------------------------------------------------------------------
__global__ __launch_bounds__(256) void counts_kernel(const bf16* __restrict__ Htb,
                                                     float* __restrict__ invc) {
  const int e = blockIdx.x;
  const bf16* row = Htb + (size_t)e * 8192;
  float s = 0.f;
  for (int i = threadIdx.x; i < 8192; i += 256) s += (float)row[i];
  __shared__ float red[256];
  red[threadIdx.x] = s;
  __syncthreads();
  for (int k = 128; k > 0; k >>= 1) {
    if (threadIdx.x < k) red[threadIdx.x] += red[threadIdx.x + k];
    __syncthreads();
  }
  if (threadIdx.x == 0) invc[e] = 1.0f / red[0];
}

// ---------------------------------------------------------------------------
// out[d] = max_e (sum_s P[s][d][e]) * invc[e]   (fused split-K reduce)
// ---------------------------------------------------------------------------
__global__ __launch_bounds__(256) void final_max(const float* __restrict__ P,
                                                 const float* __restrict__ invc,
                                                 float* __restrict__ out) {
  constexpr size_t MN = (size_t)256 * 4096;
  const int d = blockIdx.x;
  float m = -3.4e38f;
  for (int e = threadIdx.x; e < 4096; e += 256) {
    const size_t idx = (size_t)d * 4096 + e;
    const float s =
        P[idx] + P[MN + idx] + P[2 * MN + idx] + P[3 * MN + idx];
    m = fmaxf(m, s * invc[e]);
  }
  __shared__ float red[256];
  red[threadIdx.x] = m;
  __syncthreads();
  for (int k = 128; k > 0; k >>= 1) {
    if (threadIdx.x < k)
      red[threadIdx.x] = fmaxf(red[threadIdx.x], red[threadIdx.x + k]);
    __syncthreads();
  }
  if (threadIdx.x == 0) out[d] = red[0];
}

// ---------------------------------------------------------------------------
extern "C" void kernel_launch(void* const* d_in, const int* in_sizes, int n_in,
                              void* d_out, int out_size, void* d_ws,
                              size_t ws_size, hipStream_t stream) {
  const float* x0 = (const float*)d_in[0];    // [8192][256]
  const float* T = (const float*)d_in[1];     // [8192][8192]
  const float* H = (const float*)d_in[2];     // [8192][4096]
  const float* gamma = (const float*)d_in[3]; // [256]
  const float* beta = (const float*)d_in[4];  // [256]

  constexpr int Nn = 8192, E = 4096, D = 256, K = 8192;
  constexpr int S = 4;  // split-K factor

  char* w = (char*)d_ws;
  size_t off = 0;
  auto carve = [&](size_t bytes) {
    char* p = w + off;
    off += (bytes + 255) & ~(size_t)255;
    return p;
  };
  bf16* Tb = (bf16*)carve((size_t)Nn * Nn * 2);
  bf16* Tt = (bf16*)carve((size_t)Nn * Nn * 2);
  bf16* Htb = (bf16*)carve((size_t)E * Nn * 2);
  float* x0t = (float*)carve((size_t)D * Nn * 4);
  bf16* Xt = (bf16*)carve((size_t)D * Nn * 2);
  bf16* tt = (bf16*)carve((size_t)D * Nn * 2);
  bf16* stb = (bf16*)carve((size_t)D * Nn * 2);
  float* invc = (float*)carve((size_t)E * 4);
  float* P = (float*)carve((size_t)S * D * Nn * 4);  // split-K partials

  if (off > ws_size) {  // workspace too small: fail loudly (out = 0)
    hipMemsetAsync(d_out, 0, (size_t)out_size * 4, stream);
    return;
  }

  // one-time layout prep
  transpose_conv<<<dim3(128, 128), 256, 0, stream>>>(T, Nn, Nn, Tb, Tt, nullptr);
  transpose_conv<<<dim3(64, 128), 256, 0, stream>>>(H, Nn, E, nullptr, Htb, nullptr);
  transpose_conv<<<dim3(4, 128), 256, 0, stream>>>(x0, Nn, D, nullptr, Xt, x0t);
  counts_kernel<<<E, 256, 0, stream>>>(Htb, invc);

  const size_t MN = (size_t)D * Nn;
  for (int layer = 0; layer < 3; ++layer) {
    // P = split-K partials of  tt[d][j] = sum_k Xt[d][k] * Tb[j][k]
    gemm_bt<64, 128><<<dim3(64, 4, S), 256, 0, stream>>>(Xt, Tb, P, D, Nn, K,
                                                         K / S);
    reduce4_bf16<<<(int)(MN / 1024), 256, 0, stream>>>(P, tt, MN);
    // P = split-K partials of  st[d][i] = sum_j tt[d][j] * Tt[i][j]
    gemm_bt<64, 128><<<dim3(64, 4, S), 256, 0, stream>>>(tt, Tt, P, D, Nn, K,
                                                         K / S);
    if (layer < 2) {
      ln_kernel<<<dim3(256), dim3(32, 8), 0, stream>>>(P, x0t, gamma, beta, Xt);
    } else {
      reduce4_bf16<<<(int)(MN / 1024), 256, 0, stream>>>(P, stb, MN);
    }
  }

  // P = split-K partials of  sumsT[d][e] = sum_i stb[d][i] * Htb[e][i]
  gemm_bt<64, 128><<<dim3(32, 4, S), 256, 0, stream>>>(stb, Htb, P, D, E, K,
                                                       K / S);
  final_max<<<D, 256, 0, stream>>>(P, invc, (float*)d_out);
}

// Round 3
// 1090.567 us; speedup vs baseline: 1.7797x; 1.6734x over previous
//
#include <hip/hip_runtime.h>

// ---------------------------------------------------------------------------
// CasualGraph on MI355X. 3 layers of source = T^T (T x); x = LN(source+x0);
// then per-hyperedge mean of final pre-norm source, global max over edges.
// bf16 MFMA 16x16x32, fp32 accumulate.
//
// GEMM design (demand-minimizing): time ~ bytes-moved / ~4 TB/s fabric, so
//   BM = 256 = M  -> B matrix read exactly once (128 MB floor per GEMM)
//   BN = 128, split-K=4 -> 256 blocks = 1/CU; A (4 MB) re-reads hit XCD L2
//   BK = 64      -> every staged request is a full 128-B line
//   double-buffered 96 KB LDS, global_load_lds(16B), swizzle in global idx
// ---------------------------------------------------------------------------

typedef __bf16 bf16;
typedef __bf16 bf16x8 __attribute__((ext_vector_type(8)));
typedef float f32x4 __attribute__((ext_vector_type(4)));

__device__ __forceinline__ void gld_lds16(const bf16* g, bf16* l) {
  __builtin_amdgcn_global_load_lds(
      (const __attribute__((address_space(1))) unsigned int*)g,
      (__attribute__((address_space(3))) unsigned int*)l, 16, 0, 0);
}

// ---------------------------------------------------------------------------
// P[z][m][n] = sum_{k in split z} A[m][k]*B[n][k].  A,B bf16 K-contiguous.
// BM=256 (=M), BN=128, BK=64. 256 threads = 4 waves (2x2), wave tile 128x64.
// LDS row = 128 B = 8 x 16-B chunks; LDS[row][c] holds global chunk c^(row&7)
// (swizzle applied on the GLOBAL index since global_load_lds scatters
//  lane i -> base + 16*i). ds_read fragments then hit 8 bank-groups (2-way).
// ---------------------------------------------------------------------------
template <int BN>
__global__ __launch_bounds__(256) void gemm_bt(const bf16* __restrict__ A,
                                               const bf16* __restrict__ B,
                                               float* __restrict__ P,
                                               int N, int K, int Ks) {
  constexpr int BM = 256, BK = 64;
  constexpr int WM = 128, WN = BN / 2;
  constexpr int TM = WM / 16, TN = WN / 16;  // 8, WN/16
  constexpr int QA = BM / 32, QB = BN / 32;  // wave-loads per wave

  __shared__ __align__(16) bf16 As[2][BM * BK];  // 32 KB each
  __shared__ __align__(16) bf16 Bs[2][BN * BK];  // 16 KB each

  const int t = threadIdx.x, w = t >> 6, l = t & 63;
  // staging: one wave-load covers 8 rows x 128 B; lane l -> row l>>3,
  // LDS chunk l&7, which must receive global chunk (l&7)^(row&7)=(l&7)^(l>>3)
  const int srow = l >> 3;
  const int schunk = (l & 7) ^ srow;
  const int n0 = blockIdx.x * BN;
  const int kbase = blockIdx.z * Ks;

  const bf16* gA = A + (size_t)(w * 8 + srow) * K + kbase + schunk * 8;
  const bf16* gB = B + (size_t)(n0 + w * 8 + srow) * K + kbase + schunk * 8;

  auto stage = [&](int kk, int buf) {
    const size_t ko = (size_t)kk * BK;
#pragma unroll
    for (int q = 0; q < QA; ++q)
      gld_lds16(gA + (size_t)(q * 32) * K + ko,
                &As[buf][(q * 32 + w * 8) * BK]);
#pragma unroll
    for (int q = 0; q < QB; ++q)
      gld_lds16(gB + (size_t)(q * 32) * K + ko,
                &Bs[buf][(q * 32 + w * 8) * BK]);
  };

  const int lm = l & 15, kq = l >> 4;
  const int wm = (w >> 1) * WM;
  const int wn = (w & 1) * WN;

  f32x4 acc[TM][TN] = {};
  const int nk = Ks / BK;

  stage(0, 0);
  __syncthreads();

  for (int kk = 0; kk < nk; ++kk) {
    const int buf = kk & 1;
    if (kk + 1 < nk) stage(kk + 1, buf ^ 1);  // async into other buffer
#pragma unroll
    for (int ks = 0; ks < 2; ++ks) {
      const int csw = ((ks * 4 + kq) ^ (lm & 7)) * 8;  // row&7 == lm&7
      bf16x8 af[TM], bfr[TN];
#pragma unroll
      for (int i = 0; i < TM; ++i)
        af[i] = *(const bf16x8*)(&As[buf][(wm + i * 16 + lm) * BK + csw]);
#pragma unroll
      for (int j = 0; j < TN; ++j)
        bfr[j] = *(const bf16x8*)(&Bs[buf][(wn + j * 16 + lm) * BK + csw]);
#pragma unroll
      for (int i = 0; i < TM; ++i)
#pragma unroll
        for (int j = 0; j < TN; ++j)
          acc[i][j] = __builtin_amdgcn_mfma_f32_16x16x32_bf16(af[i], bfr[j],
                                                              acc[i][j], 0, 0, 0);
    }
    __syncthreads();  // compiler drains vmcnt here: buf^1 fully written
  }

  // epilogue: C/D layout col = lane&15, row = kq*4 + r
  float* Pz = P + (size_t)blockIdx.z * BM * N;
#pragma unroll
  for (int i = 0; i < TM; ++i) {
    const int mrow = wm + i * 16 + kq * 4;
#pragma unroll
    for (int j = 0; j < TN; ++j) {
      const int col = n0 + wn + j * 16 + lm;
#pragma unroll
      for (int r = 0; r < 4; ++r)
        Pz[(size_t)(mrow + r) * N + col] = acc[i][j][r];
    }
  }
}

// ---------------------------------------------------------------------------
// out[i] = bf16( sum_{s<4} P[s][i] ), float4-vectorized.
// ---------------------------------------------------------------------------
__global__ __launch_bounds__(256) void reduce4_bf16(const float* __restrict__ P,
                                                    bf16* __restrict__ out,
                                                    size_t MN) {
  const size_t i4 = ((size_t)blockIdx.x * 256 + threadIdx.x) * 4;
  if (i4 >= MN) return;
  f32x4 a = *(const f32x4*)(P + i4);
  f32x4 b = *(const f32x4*)(P + MN + i4);
  f32x4 c = *(const f32x4*)(P + 2 * MN + i4);
  f32x4 d = *(const f32x4*)(P + 3 * MN + i4);
  a = a + b + c + d;
  bf16 o[4] = {(bf16)a[0], (bf16)a[1], (bf16)a[2], (bf16)a[3]};
  *(int2*)(out + i4) = *(const int2*)o;
}

// ---------------------------------------------------------------------------
// 64x64 LDS tile transpose/convert: src [R][C] f32 ->
//   cpy [R][C] bf16 (opt), trb [C][R] bf16 (opt), trf [C][R] f32 (opt).
// ---------------------------------------------------------------------------
__global__ __launch_bounds__(256) void transpose_conv(
    const float* __restrict__ src, int R, int C, bf16* __restrict__ cpy,
    bf16* __restrict__ trb, float* __restrict__ trf) {
  __shared__ float tile[64][65];
  const int t = threadIdx.x;
  const int col = t & 63, rb4 = t >> 6;
  const int r0 = blockIdx.y * 64, c0 = blockIdx.x * 64;
#pragma unroll
  for (int rr = 0; rr < 64; rr += 4) {
    const int row = rr + rb4;
    const float v = src[(size_t)(r0 + row) * C + c0 + col];
    tile[row][col] = v;
    if (cpy) cpy[(size_t)(r0 + row) * C + c0 + col] = (bf16)v;
  }
  __syncthreads();
#pragma unroll
  for (int rr = 0; rr < 64; rr += 4) {
    const int row = rr + rb4;
    const float v = tile[col][row];
    const size_t di = (size_t)(c0 + row) * R + r0 + col;
    if (trb) trb[di] = (bf16)v;
    if (trf) trf[di] = v;
  }
}

// ---------------------------------------------------------------------------
// LayerNorm over d, fused 4-way split-K reduce. block (32 nodes, 8 d-groups)
// ---------------------------------------------------------------------------
__global__ __launch_bounds__(256) void ln_kernel(const float* __restrict__ P,
                                                 const float* __restrict__ x0t,
                                                 const float* __restrict__ gamma,
                                                 const float* __restrict__ beta,
                                                 bf16* __restrict__ Xt) {
  constexpr size_t MN = (size_t)256 * 8192;
  const int tx = threadIdx.x;
  const int ty = threadIdx.y;
  const int i = blockIdx.x * 32 + tx;
  float vbuf[32];
  float s = 0.f, s2 = 0.f;
#pragma unroll
  for (int dd = 0; dd < 32; ++dd) {
    const int d = ty * 32 + dd;
    const size_t idx = (size_t)d * 8192 + i;
    const float v = P[idx] + P[MN + idx] + P[2 * MN + idx] + P[3 * MN + idx] +
                    x0t[idx];
    vbuf[dd] = v;
    s += v;
    s2 += v * v;
  }
  __shared__ float S[8][32], Q[8][32];
  S[ty][tx] = s;
  Q[ty][tx] = s2;
  __syncthreads();
  __shared__ float MU[32], RS[32];
  if (ty == 0) {
    float a = 0.f, b = 0.f;
#pragma unroll
    for (int r = 0; r < 8; ++r) {
      a += S[r][tx];
      b += Q[r][tx];
    }
    const float mu = a * (1.0f / 256.0f);
    const float var = b * (1.0f / 256.0f) - mu * mu;
    MU[tx] = mu;
    RS[tx] = rsqrtf(var + 1e-5f);
  }
  __syncthreads();
  const float mu = MU[tx], rs = RS[tx];
#pragma unroll
  for (int dd = 0; dd < 32; ++dd) {
    const int d = ty * 32 + dd;
    const float y = (vbuf[dd] - mu) * rs * gamma[d] + beta[d];
    Xt[(size_t)d * 8192 + i] = (bf16)y;
  }
}

// ---------------------------------------------------------------------------
// inv_counts[e] = 1 / sum_i H[i][e]   (from Htb rows, coalesced)
// ---------------------------------------------------------------------------
__global__ __launch_bounds__(256) void counts_kernel(const bf16* __restrict__ Htb,
                                                     float* __restrict__ invc) {
  const int e = blockIdx.x;
  const bf16* row = Htb + (size_t)e * 8192;
  float s = 0.f;
  for (int i = threadIdx.x; i < 8192; i += 256) s += (float)row[i];
  __shared__ float red[256];
  red[threadIdx.x] = s;
  __syncthreads();
  for (int k = 128; k > 0; k >>= 1) {
    if (threadIdx.x < k) red[threadIdx.x] += red[threadIdx.x + k];
    __syncthreads();
  }
  if (threadIdx.x == 0) invc[e] = 1.0f / red[0];
}

// ---------------------------------------------------------------------------
// out[d] = max_e (sum_{s<S} P[s][d][e]) * invc[e]
// ---------------------------------------------------------------------------
__global__ __launch_bounds__(256) void final_max(const float* __restrict__ P,
                                                 const float* __restrict__ invc,
                                                 float* __restrict__ out,
                                                 int S) {
  constexpr size_t MN = (size_t)256 * 4096;
  const int d = blockIdx.x;
  float m = -3.4e38f;
  for (int e = threadIdx.x; e < 4096; e += 256) {
    const size_t idx = (size_t)d * 4096 + e;
    float s = 0.f;
    for (int z = 0; z < S; ++z) s += P[z * MN + idx];
    m = fmaxf(m, s * invc[e]);
  }
  __shared__ float red[256];
  red[threadIdx.x] = m;
  __syncthreads();
  for (int k = 128; k > 0; k >>= 1) {
    if (threadIdx.x < k)
      red[threadIdx.x] = fmaxf(red[threadIdx.x], red[threadIdx.x + k]);
    __syncthreads();
  }
  if (threadIdx.x == 0) out[d] = red[0];
}

// ---------------------------------------------------------------------------
extern "C" void kernel_launch(void* const* d_in, const int* in_sizes, int n_in,
                              void* d_out, int out_size, void* d_ws,
                              size_t ws_size, hipStream_t stream) {
  const float* x0 = (const float*)d_in[0];    // [8192][256]
  const float* T = (const float*)d_in[1];     // [8192][8192]
  const float* H = (const float*)d_in[2];     // [8192][4096]
  const float* gamma = (const float*)d_in[3]; // [256]
  const float* beta = (const float*)d_in[4];  // [256]

  constexpr int Nn = 8192, E = 4096, D = 256, K = 8192;

  char* w = (char*)d_ws;
  size_t off = 0;
  auto carve = [&](size_t bytes) {
    char* p = w + off;
    off += (bytes + 255) & ~(size_t)255;
    return p;
  };
  bf16* Tb = (bf16*)carve((size_t)Nn * Nn * 2);
  bf16* Tt = (bf16*)carve((size_t)Nn * Nn * 2);
  bf16* Htb = (bf16*)carve((size_t)E * Nn * 2);
  float* x0t = (float*)carve((size_t)D * Nn * 4);
  bf16* Xt = (bf16*)carve((size_t)D * Nn * 2);
  bf16* tt = (bf16*)carve((size_t)D * Nn * 2);
  bf16* stb = (bf16*)carve((size_t)D * Nn * 2);
  float* invc = (float*)carve((size_t)E * 4);
  float* P = (float*)carve((size_t)4 * D * Nn * 4);  // 32 MB partials

  if (off > ws_size) {  // workspace too small: fail loudly (out = 0)
    hipMemsetAsync(d_out, 0, (size_t)out_size * 4, stream);
    return;
  }

  // one-time layout prep
  transpose_conv<<<dim3(128, 128), 256, 0, stream>>>(T, Nn, Nn, Tb, Tt, nullptr);
  transpose_conv<<<dim3(64, 128), 256, 0, stream>>>(H, Nn, E, nullptr, Htb, nullptr);
  transpose_conv<<<dim3(4, 128), 256, 0, stream>>>(x0, Nn, D, nullptr, Xt, x0t);
  counts_kernel<<<E, 256, 0, stream>>>(Htb, invc);

  const size_t MN = (size_t)D * Nn;
  for (int layer = 0; layer < 3; ++layer) {
    // P = split-K partials of  tt[d][j] = sum_k Xt[d][k] * Tb[j][k]
    gemm_bt<128><<<dim3(64, 1, 4), 256, 0, stream>>>(Xt, Tb, P, Nn, K, K / 4);
    reduce4_bf16<<<(int)(MN / 1024), 256, 0, stream>>>(P, tt, MN);
    // P = split-K partials of  st[d][i] = sum_j tt[d][j] * Tt[i][j]
    gemm_bt<128><<<dim3(64, 1, 4), 256, 0, stream>>>(tt, Tt, P, Nn, K, K / 4);
    if (layer < 2) {
      ln_kernel<<<dim3(256), dim3(32, 8), 0, stream>>>(P, x0t, gamma, beta, Xt);
    } else {
      reduce4_bf16<<<(int)(MN / 1024), 256, 0, stream>>>(P, stb, MN);
    }
  }

  // P = split-K(8) partials of  sumsT[d][e] = sum_i stb[d][i] * Htb[e][i]
  gemm_bt<128><<<dim3(32, 1, 8), 256, 0, stream>>>(stb, Htb, P, E, K, K / 8);
  final_max<<<D, 256, 0, stream>>>(P, invc, (float*)d_out, 8);
}